// Round 6
// baseline (205.516 us; speedup 1.0000x reference)
//
#include <hip/hip_runtime.h>

// NT-Xent loss, B=4096, D=256, N=16384, T=0.5.
// loss = mean_i( -pos_i + log(sum_{j!=i} exp(2*dot(zn_i, zn_j)) + 1e-12) )
//
// R8: R2-champion occupancy + R7 pipeline.
//  - 128x128 upper-tri tiles (8256 blocks), 4 waves (2x2), per-wave 64x64:
//    acc 4x4 = 64 AGPR -> 128 unified regs/thread -> 4 blocks/CU (reg-capped class).
//  - BK=32, DOUBLE-buffered 2x16KB LDS, 1-deep prefetch, counted vmcnt(4) gates
//    (never drain mid-loop), 2 raw barriers per K-tile.
//  - 3-bit granule swizzle slot = g ^ (line&7) on pair-packed 128B lines (0 conflicts).
//  - Collapsed scalar addressing (no arrays -> no spill; WRITE_SIZE is the tripwire).
//  - Reduction scratch aliased into buf0 after the K-loop: LDS stays 32KB.
//  - exp2-fold (zb scaled by sqrt(2*log2 e)); XCD-chunked block swizzle (8256=8*1032).
//
// ws layout:
//   [0, 8MB)                  : zb   — l2-normalized z * 1.6986436, bf16, [16384][256]
//   [8MB, +8.0625MB)          : part — f32 [8256][256] (128 row-sums + 128 col-sums)
//   [POS_OFF, +16KB)          : pospart[4096]
//   [LOG_OFF, +256B)          : logpart[64]
//   [CNT_OFF]                 : cnt (uint) — reset by norm4k every launch

typedef __bf16 bf16;
typedef __bf16 bf16x4 __attribute__((ext_vector_type(4)));
typedef __bf16 bf16x8 __attribute__((ext_vector_type(8)));
typedef float  f32x4  __attribute__((ext_vector_type(4)));

#define NTOT 16384
#define DDIM 256
// sqrt(2*log2(e)) : dot of scaled vectors = 2*log2(e)*dot, so exp2(acc)=exp(2*dot)
#define KSCL 1.6986436f

__device__ __forceinline__ float dot4(float4 a, float4 b) {
    return a.x * b.x + a.y * b.y + a.z * b.z + a.w * b.w;
}

// ---------------- kernel 1: normalize rows -> bf16 (scaled), plus positive-pair sims ----------------
__global__ __launch_bounds__(256) void norm4k(const float* __restrict__ z1,
                                              const float* __restrict__ z2,
                                              const float* __restrict__ z3,
                                              const float* __restrict__ z4,
                                              bf16* __restrict__ zb,
                                              float* __restrict__ pospart,
                                              unsigned* __restrict__ cnt) {
    if (blockIdx.x == 0 && threadIdx.x == 0) *cnt = 0u; // arm last-block-done for rowlogf
    const int wave = threadIdx.x >> 6;
    const int lane = threadIdx.x & 63;
    const int i    = blockIdx.x * 4 + wave; // 0..4095
    const float4* p1 = (const float4*)(z1 + (size_t)i * DDIM);
    const float4* p2 = (const float4*)(z2 + (size_t)i * DDIM);
    const float4* p3 = (const float4*)(z3 + (size_t)i * DDIM);
    const float4* p4 = (const float4*)(z4 + (size_t)i * DDIM);
    float4 a = p1[lane], b = p2[lane], c = p3[lane], d = p4[lane];
    float s11 = dot4(a, a), s22 = dot4(b, b), s33 = dot4(c, c), s44 = dot4(d, d);
    float s12 = dot4(a, b), s23 = dot4(b, c), s34 = dot4(c, d), s41 = dot4(d, a);
#pragma unroll
    for (int m = 32; m >= 1; m >>= 1) {
        s11 += __shfl_xor(s11, m, 64); s22 += __shfl_xor(s22, m, 64);
        s33 += __shfl_xor(s33, m, 64); s44 += __shfl_xor(s44, m, 64);
        s12 += __shfl_xor(s12, m, 64); s23 += __shfl_xor(s23, m, 64);
        s34 += __shfl_xor(s34, m, 64); s41 += __shfl_xor(s41, m, 64);
    }
    const float m1 = fmaxf(sqrtf(s11), 1e-12f), m2 = fmaxf(sqrtf(s22), 1e-12f);
    const float m3 = fmaxf(sqrtf(s33), 1e-12f), m4 = fmaxf(sqrtf(s44), 1e-12f);
    const float i1 = 1.0f / m1, i2 = 1.0f / m2, i3 = 1.0f / m3, i4 = 1.0f / m4;
    const float t1 = i1 * KSCL, t2 = i2 * KSCL, t3 = i3 * KSCL, t4 = i4 * KSCL;
    bf16x4 o;
    o.x = (bf16)(a.x * t1); o.y = (bf16)(a.y * t1); o.z = (bf16)(a.z * t1); o.w = (bf16)(a.w * t1);
    *(bf16x4*)(zb + (size_t)i * DDIM + lane * 4) = o;
    o.x = (bf16)(b.x * t2); o.y = (bf16)(b.y * t2); o.z = (bf16)(b.z * t2); o.w = (bf16)(b.w * t2);
    *(bf16x4*)(zb + (size_t)(i + 4096) * DDIM + lane * 4) = o;
    o.x = (bf16)(c.x * t3); o.y = (bf16)(c.y * t3); o.z = (bf16)(c.z * t3); o.w = (bf16)(c.w * t3);
    *(bf16x4*)(zb + (size_t)(i + 8192) * DDIM + lane * 4) = o;
    o.x = (bf16)(d.x * t4); o.y = (bf16)(d.y * t4); o.z = (bf16)(d.z * t4); o.w = (bf16)(d.w * t4);
    *(bf16x4*)(zb + (size_t)(i + 12288) * DDIM + lane * 4) = o;
    if (lane == 0)
        pospart[i] = 2.0f * (s12 * i1 * i2 + s23 * i2 * i3 + s34 * i3 * i4 + s41 * i4 * i1);
}

// ---------------- kernel 2: fused Gram-matrix exp-rowsum, upper triangle ----------------
__global__ __launch_bounds__(256, 4) void tilek(const bf16* __restrict__ zb,
                                                float* __restrict__ part) {
    // 2 buffers x 16KB (A:8KB + B:8KB). Reductions aliased into buf0 after K-loop.
    __shared__ __attribute__((aligned(16))) char lds[32768];

    const int tid  = threadIdx.x;
    const int wave = tid >> 6;
    const int lane = tid & 63;
    const int quad = lane >> 4;
    const int l15  = lane & 15;
    const int wr   = wave >> 1;   // 0..1 row half (64 rows of 128)
    const int wc   = wave & 1;    // 0..1 col half (64 cols of 128)

    // XCD-chunked swizzle (bijective: 8256 = 8*1032), then triangular decode:
    // k -> (R, C), R <= C over 128 row-blocks; f(R) = R*128 - R*(R-1)/2
    const int k = (blockIdx.x & 7) * 1032 + (blockIdx.x >> 3);
    int R = (int)((257.0 - sqrt(257.0 * 257.0 - 8.0 * (double)k)) * 0.5);
    if (R > 127) R = 127;
    while (R < 127 && ((R + 1) * 128 - ((R + 1) * R) / 2) <= k) ++R;
    while (R > 0 && (R * 128 - (R * (R - 1)) / 2) > k) --R;
    const int C = R + (k - (R * 128 - (R * (R - 1)) / 2));
    const int dRC = (R - C) << 7; // 0 on diag; <= -128 off-diag (mask vacuous there)

    // ---- staging addressing (collapsed): pair-packed 128B lines, slot = g ^ (line&7) ----
    // Per K-tile: A = 128 rows x 64B = 8KB = 512 granules (2 loads/thread); B same at +8192.
    // chunk i: granule d = i*256+tid, line = i*32+(tid>>3); i*32 === 0 (mod 8) -> g invariant:
    //   src(i) = src0 + i*32768, dst(i) = tid*16 + i*4096.
    const int L0 = tid >> 3;
    const int g0 = (tid & 7) ^ (L0 & 7);
    const int srcoff = (2 * L0 + (g0 >> 2)) * 512 + ((g0 & 3) << 4);
    const char* gA0 = (const char*)zb + (size_t)(R << 7) * 512 + srcoff;
    const char* gB0 = (const char*)zb + (size_t)(C << 7) * 512 + srcoff;
    const int dst0 = tid << 4;

    auto STAGE = [&](int t, int bb) { // t = K-tile (0..7) -> +t*64B per row; bb = buffer base
#pragma unroll
        for (int i = 0; i < 2; ++i)
            __builtin_amdgcn_global_load_lds(
                (const __attribute__((address_space(1))) unsigned int*)(gA0 + (i << 15) + (t << 6)),
                (__attribute__((address_space(3))) unsigned int*)(lds + bb + (i << 12) + dst0),
                16, 0, 0);
#pragma unroll
        for (int i = 0; i < 2; ++i)
            __builtin_amdgcn_global_load_lds(
                (const __attribute__((address_space(1))) unsigned int*)(gB0 + (i << 15) + (t << 6)),
                (__attribute__((address_space(3))) unsigned int*)(lds + bb + 8192 + (i << 12) + dst0),
                16, 0, 0);
    };

    // ---- ds_read addressing (collapsed): off(rt) = off0 + rt*1024 ----
    // row(rt) = wr*64 + rt*16 + l15 -> line advances by 8 -> line&7, granule invariant.
    const int sw    = ((((l15 & 1) << 2) | quad) ^ (l15 >> 1)) << 4;
    const int offA0 = (wr << 12) + ((l15 >> 1) << 7) + sw;
    const int offB0 = 8192 + (wc << 12) + ((l15 >> 1) << 7) + sw;

    f32x4 zero = {0.f, 0.f, 0.f, 0.f};
    f32x4 acc[4][4];
#pragma unroll
    for (int a = 0; a < 4; ++a)
#pragma unroll
        for (int b = 0; b < 4; ++b) acc[a][b] = zero;

    // prologue: stage K-tile 0 into buffer 0 (4 loads/thread)
    STAGE(0, 0);

#pragma unroll
    for (int ko = 0; ko < 8; ++ko) {
        const int bb = (ko & 1) << 14;
        if (ko < 7) STAGE(ko + 1, (~ko & 1) << 14); // 1-deep prefetch into other buffer
        // gate: this K-tile's 4 loads done; next tile's 4 stay in flight
        if (ko < 7) asm volatile("s_waitcnt vmcnt(4)" ::: "memory");
        else        asm volatile("s_waitcnt vmcnt(0)" ::: "memory");
        __builtin_amdgcn_s_barrier();      // b1: buf[ko&1] staged by all waves
        __builtin_amdgcn_sched_barrier(0);

        bf16x8 af[4], bfr[4];
#pragma unroll
        for (int rt = 0; rt < 4; ++rt)
            af[rt] = *(const bf16x8*)(lds + bb + offA0 + (rt << 10));
#pragma unroll
        for (int ct = 0; ct < 4; ++ct)
            bfr[ct] = *(const bf16x8*)(lds + bb + offB0 + (ct << 10));

        __builtin_amdgcn_s_setprio(1);
#pragma unroll
        for (int rt = 0; rt < 4; ++rt)
#pragma unroll
            for (int ct = 0; ct < 4; ++ct)
                acc[rt][ct] = __builtin_amdgcn_mfma_f32_16x16x32_bf16(
                    af[rt], bfr[ct], acc[rt][ct], 0, 0, 0);
        __builtin_amdgcn_s_setprio(0);
        __builtin_amdgcn_s_barrier();      // b2: all waves done reading buf[ko&1]
        __builtin_amdgcn_sched_barrier(0);
    }

    // epilogue: e = exp2(acc) = exp(2*dot); mask r==c on diag tiles (vacuous off-diag).
    // Reduction scratch aliased into buf0 (all LDS reads finished at b2(7), a real barrier).
    float* rsum = (float*)lds;            // [2][128]: [wc][row-local]
    float* csum = (float*)(lds + 1024);   // [2][128]: [wr][col-local]
    float cs[4] = {0.f, 0.f, 0.f, 0.f};
#pragma unroll
    for (int rt = 0; rt < 4; ++rt) {
        float rs[4] = {0.f, 0.f, 0.f, 0.f};
        const int rloc = (wr << 6) + (rt << 4) + (quad << 2); // + rr = row-local 0..127
#pragma unroll
        for (int ct = 0; ct < 4; ++ct) {
            const int cloc = (wc << 6) + (ct << 4) + l15;     // col-local 0..127
#pragma unroll
            for (int rr = 0; rr < 4; ++rr) {
                float e;
                asm("v_exp_f32 %0, %1" : "=v"(e) : "v"(acc[rt][ct][rr]));
                if (rloc + rr + dRC == cloc) e = 0.f; // self-sim (diag tiles only)
                rs[rr] += e;
                cs[ct] += e;
            }
        }
        // row-sums: reduce across 16 lanes (C-layout: col = lane&15)
#pragma unroll
        for (int m = 1; m <= 8; m <<= 1)
#pragma unroll
            for (int rr = 0; rr < 4; ++rr) rs[rr] += __shfl_xor(rs[rr], m, 64);
        if (l15 == 0) {
#pragma unroll
            for (int rr = 0; rr < 4; ++rr) rsum[(wc << 7) + rloc + rr] = rs[rr];
        }
    }
    // col-sums: reduce across the 4 quads (rows), lanes 16 apart
#pragma unroll
    for (int m = 16; m <= 32; m <<= 1)
#pragma unroll
        for (int ct = 0; ct < 4; ++ct) cs[ct] += __shfl_xor(cs[ct], m, 64);
    if (quad == 0) {
#pragma unroll
        for (int ct = 0; ct < 4; ++ct) csum[(wr << 7) + (wc << 6) + (ct << 4) + l15] = cs[ct];
    }
    __syncthreads();
    float* pt = part + (size_t)k * 256;
    if (tid < 128) {
        pt[tid] = rsum[tid] + rsum[128 + tid];
    } else if (R != C) {
        const int c = tid - 128;
        pt[128 + c] = csum[c] + csum[128 + c];
    }
}

// ---------------- kernel 3: per-row reduce + log; last block finalizes ----------------
__global__ __launch_bounds__(256) void rowlogf(const float* __restrict__ part,
                                               const float* __restrict__ pospart,
                                               float* __restrict__ logpart,
                                               unsigned* __restrict__ cnt,
                                               float* __restrict__ out) {
    const int r  = blockIdx.x * 256 + threadIdx.x; // 0..16383
    const int R  = r >> 7;
    const int rl = r & 127;
    const int fR = R * 128 - (R * (R - 1)) / 2;
    float s = 0.f;
    // row-partials: tiles (R, C) for C = R..127 -> contiguous idx [fR, fR+128-R)
    const int n1 = 128 - R;
    const float* p1 = part + (size_t)fR * 256 + rl;
#pragma unroll 4
    for (int j = 0; j < n1; ++j) s += p1[(size_t)j * 256];
    // col-partials: tiles (R2, R) for R2 = 0..R-1; idx(R2) = f(R2) + R - R2
    int idx = R; // R2 = 0
    for (int R2 = 0; R2 < R; ++R2) {
        s += part[(size_t)idx * 256 + 128 + rl];
        idx += 127 - R2;
    }
    float lg = logf(s + 1e-12f);
#pragma unroll
    for (int m = 32; m >= 1; m >>= 1) lg += __shfl_xor(lg, m, 64);
    __shared__ float red[4];
    const int wave = threadIdx.x >> 6, lane = threadIdx.x & 63;
    if (lane == 0) red[wave] = lg;
    __syncthreads();
    if (threadIdx.x == 0) logpart[blockIdx.x] = red[0] + red[1] + red[2] + red[3];

    // last-block-done: winner reduces pospart + logpart
    __shared__ unsigned done;
    __threadfence();
    if (threadIdx.x == 0) done = atomicAdd(cnt, 1u);
    __syncthreads();
    if (done == 63) {
        __threadfence();
        const int t = threadIdx.x;
        float sp = 0.f, sl = 0.f;
        for (int kk = t; kk < 4096; kk += 256) sp += pospart[kk];
        if (t < 64) sl = logpart[t];
#pragma unroll
        for (int m = 32; m >= 1; m >>= 1) { sp += __shfl_xor(sp, m, 64); sl += __shfl_xor(sl, m, 64); }
        __shared__ float rp[4], rl2[4];
        if (lane == 0) { rp[wave] = sp; rl2[wave] = sl; }
        __syncthreads();
        if (t == 0) {
            float P = rp[0] + rp[1] + rp[2] + rp[3];
            float L = rl2[0] + rl2[1] + rl2[2] + rl2[3];
            out[0] = (L - P) / 16384.0f;
        }
    }
}

extern "C" void kernel_launch(void* const* d_in, const int* in_sizes, int n_in,
                              void* d_out, int out_size, void* d_ws, size_t ws_size,
                              hipStream_t stream) {
    const float* z1 = (const float*)d_in[0];
    const float* z2 = (const float*)d_in[1];
    const float* z3 = (const float*)d_in[2];
    const float* z4 = (const float*)d_in[3];
    float* out = (float*)d_out;

    const size_t PART_OFF = (size_t)(8u << 20);              // 8 MB
    const size_t POS_OFF  = PART_OFF + (size_t)8256 * 256 * 4; // 16,842,752
    const size_t LOG_OFF  = POS_OFF + 16384;
    const size_t CNT_OFF  = LOG_OFF + 256;

    char* ws = (char*)d_ws;
    bf16*  zb      = (bf16*)ws;
    float* part    = (float*)(ws + PART_OFF);
    float* pospart = (float*)(ws + POS_OFF);
    float* logpart = (float*)(ws + LOG_OFF);
    unsigned* cnt  = (unsigned*)(ws + CNT_OFF);

    norm4k<<<1024, 256, 0, stream>>>(z1, z2, z3, z4, zb, pospart, cnt);
    tilek<<<8256, 256, 0, stream>>>(zb, part);
    rowlogf<<<64, 256, 0, stream>>>(part, pospart, logpart, cnt, out);
}

// Round 7
// 189.092 us; speedup vs baseline: 1.0869x; 1.0869x over previous
//
#include <hip/hip_runtime.h>

// NT-Xent loss, B=4096, D=256, N=16384, T=0.5.
// loss = mean_i( -pos_i + log(sum_{j!=i} exp(2*dot(zn_i, zn_j)) + 1e-12) )
//
// R9: tilek frozen at R8's best-measured structure (128x128 upper-tri tiles, 4 waves
// 2x2 of 64x64, BK=32, double-buffered 2x16KB LDS, 1-deep prefetch, counted vmcnt(4),
// 2 raw barriers/K-tile, 3-bit granule swizzle, collapsed scalar addressing,
// 4 blocks/CU). Changes vs R8 are tail-only:
//  - part back to R2's column-major [128 colblocks][16384 rows] (coalesced tail reads;
//    same summation order as the R2 champion).
//  - rowlogf: 256 blocks, 4 threads/row x 32 colblocks each, shfl combine, fused
//    final reduction via last-block-done atomic (target 256).
//
// ws layout:
//   [0, 8MB)        : zb   — l2-normalized z * 1.6986436, bf16, [16384][256]
//   [8MB, 16MB)     : part — f32 [128][16384] (column-block partial sums)
//   [16MB, +16KB)   : pospart[4096]
//   [+16KB, +1KB)   : logpart[256]
//   [then]          : cnt (uint) — reset by norm4k every launch

typedef __bf16 bf16;
typedef __bf16 bf16x4 __attribute__((ext_vector_type(4)));
typedef __bf16 bf16x8 __attribute__((ext_vector_type(8)));
typedef float  f32x4  __attribute__((ext_vector_type(4)));

#define NTOT 16384
#define DDIM 256
// sqrt(2*log2(e)) : dot of scaled vectors = 2*log2(e)*dot, so exp2(acc)=exp(2*dot)
#define KSCL 1.6986436f

__device__ __forceinline__ float dot4(float4 a, float4 b) {
    return a.x * b.x + a.y * b.y + a.z * b.z + a.w * b.w;
}

// ---------------- kernel 1: normalize rows -> bf16 (scaled), plus positive-pair sims ----------------
__global__ __launch_bounds__(256) void norm4k(const float* __restrict__ z1,
                                              const float* __restrict__ z2,
                                              const float* __restrict__ z3,
                                              const float* __restrict__ z4,
                                              bf16* __restrict__ zb,
                                              float* __restrict__ pospart,
                                              unsigned* __restrict__ cnt) {
    if (blockIdx.x == 0 && threadIdx.x == 0) *cnt = 0u; // arm last-block-done for rowlogf
    const int wave = threadIdx.x >> 6;
    const int lane = threadIdx.x & 63;
    const int i    = blockIdx.x * 4 + wave; // 0..4095
    const float4* p1 = (const float4*)(z1 + (size_t)i * DDIM);
    const float4* p2 = (const float4*)(z2 + (size_t)i * DDIM);
    const float4* p3 = (const float4*)(z3 + (size_t)i * DDIM);
    const float4* p4 = (const float4*)(z4 + (size_t)i * DDIM);
    float4 a = p1[lane], b = p2[lane], c = p3[lane], d = p4[lane];
    float s11 = dot4(a, a), s22 = dot4(b, b), s33 = dot4(c, c), s44 = dot4(d, d);
    float s12 = dot4(a, b), s23 = dot4(b, c), s34 = dot4(c, d), s41 = dot4(d, a);
#pragma unroll
    for (int m = 32; m >= 1; m >>= 1) {
        s11 += __shfl_xor(s11, m, 64); s22 += __shfl_xor(s22, m, 64);
        s33 += __shfl_xor(s33, m, 64); s44 += __shfl_xor(s44, m, 64);
        s12 += __shfl_xor(s12, m, 64); s23 += __shfl_xor(s23, m, 64);
        s34 += __shfl_xor(s34, m, 64); s41 += __shfl_xor(s41, m, 64);
    }
    const float m1 = fmaxf(sqrtf(s11), 1e-12f), m2 = fmaxf(sqrtf(s22), 1e-12f);
    const float m3 = fmaxf(sqrtf(s33), 1e-12f), m4 = fmaxf(sqrtf(s44), 1e-12f);
    const float i1 = 1.0f / m1, i2 = 1.0f / m2, i3 = 1.0f / m3, i4 = 1.0f / m4;
    const float t1 = i1 * KSCL, t2 = i2 * KSCL, t3 = i3 * KSCL, t4 = i4 * KSCL;
    bf16x4 o;
    o.x = (bf16)(a.x * t1); o.y = (bf16)(a.y * t1); o.z = (bf16)(a.z * t1); o.w = (bf16)(a.w * t1);
    *(bf16x4*)(zb + (size_t)i * DDIM + lane * 4) = o;
    o.x = (bf16)(b.x * t2); o.y = (bf16)(b.y * t2); o.z = (bf16)(b.z * t2); o.w = (bf16)(b.w * t2);
    *(bf16x4*)(zb + (size_t)(i + 4096) * DDIM + lane * 4) = o;
    o.x = (bf16)(c.x * t3); o.y = (bf16)(c.y * t3); o.z = (bf16)(c.z * t3); o.w = (bf16)(c.w * t3);
    *(bf16x4*)(zb + (size_t)(i + 8192) * DDIM + lane * 4) = o;
    o.x = (bf16)(d.x * t4); o.y = (bf16)(d.y * t4); o.z = (bf16)(d.z * t4); o.w = (bf16)(d.w * t4);
    *(bf16x4*)(zb + (size_t)(i + 12288) * DDIM + lane * 4) = o;
    if (lane == 0)
        pospart[i] = 2.0f * (s12 * i1 * i2 + s23 * i2 * i3 + s34 * i3 * i4 + s41 * i4 * i1);
}

// ---------------- kernel 2: fused Gram-matrix exp-rowsum, upper triangle ----------------
__global__ __launch_bounds__(256, 4) void tilek(const bf16* __restrict__ zb,
                                                float* __restrict__ part) {
    // 2 buffers x 16KB (A:8KB + B:8KB). Reductions aliased into buf0 after K-loop.
    __shared__ __attribute__((aligned(16))) char lds[32768];

    const int tid  = threadIdx.x;
    const int wave = tid >> 6;
    const int lane = tid & 63;
    const int quad = lane >> 4;
    const int l15  = lane & 15;
    const int wr   = wave >> 1;   // 0..1 row half (64 rows of 128)
    const int wc   = wave & 1;    // 0..1 col half (64 cols of 128)

    // XCD-chunked swizzle (bijective: 8256 = 8*1032), then triangular decode:
    // k -> (R, C), R <= C over 128 row-blocks; f(R) = R*128 - R*(R-1)/2
    const int k = (blockIdx.x & 7) * 1032 + (blockIdx.x >> 3);
    int R = (int)((257.0 - sqrt(257.0 * 257.0 - 8.0 * (double)k)) * 0.5);
    if (R > 127) R = 127;
    while (R < 127 && ((R + 1) * 128 - ((R + 1) * R) / 2) <= k) ++R;
    while (R > 0 && (R * 128 - (R * (R - 1)) / 2) > k) --R;
    const int C = R + (k - (R * 128 - (R * (R - 1)) / 2));
    const int dRC = (R - C) << 7; // 0 on diag; <= -128 off-diag (mask vacuous there)

    // ---- staging addressing (collapsed): pair-packed 128B lines, slot = g ^ (line&7) ----
    // Per K-tile: A = 128 rows x 64B = 8KB = 512 granules (2 loads/thread); B same at +8192.
    // chunk i: granule d = i*256+tid, line = i*32+(tid>>3); i*32 === 0 (mod 8) -> g invariant:
    //   src(i) = src0 + i*32768, dst(i) = tid*16 + i*4096.
    const int L0 = tid >> 3;
    const int g0 = (tid & 7) ^ (L0 & 7);
    const int srcoff = (2 * L0 + (g0 >> 2)) * 512 + ((g0 & 3) << 4);
    const char* gA0 = (const char*)zb + (size_t)(R << 7) * 512 + srcoff;
    const char* gB0 = (const char*)zb + (size_t)(C << 7) * 512 + srcoff;
    const int dst0 = tid << 4;

    auto STAGE = [&](int t, int bb) { // t = K-tile (0..7) -> +t*64B per row; bb = buffer base
#pragma unroll
        for (int i = 0; i < 2; ++i)
            __builtin_amdgcn_global_load_lds(
                (const __attribute__((address_space(1))) unsigned int*)(gA0 + (i << 15) + (t << 6)),
                (__attribute__((address_space(3))) unsigned int*)(lds + bb + (i << 12) + dst0),
                16, 0, 0);
#pragma unroll
        for (int i = 0; i < 2; ++i)
            __builtin_amdgcn_global_load_lds(
                (const __attribute__((address_space(1))) unsigned int*)(gB0 + (i << 15) + (t << 6)),
                (__attribute__((address_space(3))) unsigned int*)(lds + bb + 8192 + (i << 12) + dst0),
                16, 0, 0);
    };

    // ---- ds_read addressing (collapsed): off(rt) = off0 + rt*1024 ----
    // row(rt) = wr*64 + rt*16 + l15 -> line advances by 8 -> line&7, granule invariant.
    const int sw    = ((((l15 & 1) << 2) | quad) ^ (l15 >> 1)) << 4;
    const int offA0 = (wr << 12) + ((l15 >> 1) << 7) + sw;
    const int offB0 = 8192 + (wc << 12) + ((l15 >> 1) << 7) + sw;

    f32x4 zero = {0.f, 0.f, 0.f, 0.f};
    f32x4 acc[4][4];
#pragma unroll
    for (int a = 0; a < 4; ++a)
#pragma unroll
        for (int b = 0; b < 4; ++b) acc[a][b] = zero;

    // prologue: stage K-tile 0 into buffer 0 (4 loads/thread)
    STAGE(0, 0);

#pragma unroll
    for (int ko = 0; ko < 8; ++ko) {
        const int bb = (ko & 1) << 14;
        if (ko < 7) STAGE(ko + 1, (~ko & 1) << 14); // 1-deep prefetch into other buffer
        // gate: this K-tile's 4 loads done; next tile's 4 stay in flight
        if (ko < 7) asm volatile("s_waitcnt vmcnt(4)" ::: "memory");
        else        asm volatile("s_waitcnt vmcnt(0)" ::: "memory");
        __builtin_amdgcn_s_barrier();      // b1: buf[ko&1] staged by all waves
        __builtin_amdgcn_sched_barrier(0);

        bf16x8 af[4], bfr[4];
#pragma unroll
        for (int rt = 0; rt < 4; ++rt)
            af[rt] = *(const bf16x8*)(lds + bb + offA0 + (rt << 10));
#pragma unroll
        for (int ct = 0; ct < 4; ++ct)
            bfr[ct] = *(const bf16x8*)(lds + bb + offB0 + (ct << 10));

        __builtin_amdgcn_s_setprio(1);
#pragma unroll
        for (int rt = 0; rt < 4; ++rt)
#pragma unroll
            for (int ct = 0; ct < 4; ++ct)
                acc[rt][ct] = __builtin_amdgcn_mfma_f32_16x16x32_bf16(
                    af[rt], bfr[ct], acc[rt][ct], 0, 0, 0);
        __builtin_amdgcn_s_setprio(0);
        __builtin_amdgcn_s_barrier();      // b2: all waves done reading buf[ko&1]
        __builtin_amdgcn_sched_barrier(0);
    }

    // epilogue: e = exp2(acc) = exp(2*dot); mask r==c on diag tiles (vacuous off-diag).
    // Reduction scratch aliased into buf0 (all LDS reads finished at b2(7), a real barrier).
    float* rsum = (float*)lds;            // [2][128]: [wc][row-local]
    float* csum = (float*)(lds + 1024);   // [2][128]: [wr][col-local]
    float cs[4] = {0.f, 0.f, 0.f, 0.f};
#pragma unroll
    for (int rt = 0; rt < 4; ++rt) {
        float rs[4] = {0.f, 0.f, 0.f, 0.f};
        const int rloc = (wr << 6) + (rt << 4) + (quad << 2); // + rr = row-local 0..127
#pragma unroll
        for (int ct = 0; ct < 4; ++ct) {
            const int cloc = (wc << 6) + (ct << 4) + l15;     // col-local 0..127
#pragma unroll
            for (int rr = 0; rr < 4; ++rr) {
                float e;
                asm("v_exp_f32 %0, %1" : "=v"(e) : "v"(acc[rt][ct][rr]));
                if (rloc + rr + dRC == cloc) e = 0.f; // self-sim (diag tiles only)
                rs[rr] += e;
                cs[ct] += e;
            }
        }
        // row-sums: reduce across 16 lanes (C-layout: col = lane&15)
#pragma unroll
        for (int m = 1; m <= 8; m <<= 1)
#pragma unroll
            for (int rr = 0; rr < 4; ++rr) rs[rr] += __shfl_xor(rs[rr], m, 64);
        if (l15 == 0) {
#pragma unroll
            for (int rr = 0; rr < 4; ++rr) rsum[(wc << 7) + rloc + rr] = rs[rr];
        }
    }
    // col-sums: reduce across the 4 quads (rows), lanes 16 apart
#pragma unroll
    for (int m = 16; m <= 32; m <<= 1)
#pragma unroll
        for (int ct = 0; ct < 4; ++ct) cs[ct] += __shfl_xor(cs[ct], m, 64);
    if (quad == 0) {
#pragma unroll
        for (int ct = 0; ct < 4; ++ct) csum[(wr << 7) + (wc << 6) + (ct << 4) + l15] = cs[ct];
    }
    __syncthreads();
    // column-major part [cblk][row]: rowsums -> cblk C, rows Rbase+tid;
    // colsums -> cblk R, rows Cbase+c. Exactly-once coverage (R2-proven).
    if (tid < 128) {
        part[(size_t)C * NTOT + (R << 7) + tid] = rsum[tid] + rsum[128 + tid];
    } else if (R != C) {
        const int c = tid - 128;
        part[(size_t)R * NTOT + (C << 7) + c] = csum[c] + csum[128 + c];
    }
}

// ---------------- kernel 3: per-row reduce + log; last block finalizes ----------------
// 256 blocks x 256 threads; 4 threads per row, each sums 32 column-blocks (coalesced).
__global__ __launch_bounds__(256) void rowlogf(const float* __restrict__ part,
                                               const float* __restrict__ pospart,
                                               float* __restrict__ logpart,
                                               unsigned* __restrict__ cnt,
                                               float* __restrict__ out) {
    const int t  = threadIdx.x;
    const int r  = blockIdx.x * 64 + (t >> 2);   // row 0..16383
    const int c0 = (t & 3) * 32;                 // this thread's column-block range
    float s = 0.f;
#pragma unroll 8
    for (int j = 0; j < 32; ++j) s += part[(size_t)(c0 + j) * NTOT + r];
    // combine the 4 partials of each row (lanes 4q..4q+3)
    s += __shfl_xor(s, 1, 64);
    s += __shfl_xor(s, 2, 64);
    float v = ((t & 3) == 0) ? logf(s + 1e-12f) : 0.f;
    // sum the 16 row-logs of this wave (butterfly over bits 2..5)
#pragma unroll
    for (int m = 4; m <= 32; m <<= 1) v += __shfl_xor(v, m, 64);
    __shared__ float red[4];
    const int wave = t >> 6, lane = t & 63;
    if (lane == 0) red[wave] = v;
    __syncthreads();
    if (t == 0) logpart[blockIdx.x] = red[0] + red[1] + red[2] + red[3];

    // last-block-done: winner reduces pospart + logpart
    __shared__ unsigned done;
    __threadfence();
    if (t == 0) done = atomicAdd(cnt, 1u);
    __syncthreads();
    if (done == 255) {
        __threadfence();
        float sp = 0.f;
#pragma unroll
        for (int kk = t; kk < 4096; kk += 256) sp += pospart[kk];
        float sl = logpart[t];
#pragma unroll
        for (int m = 32; m >= 1; m >>= 1) { sp += __shfl_xor(sp, m, 64); sl += __shfl_xor(sl, m, 64); }
        __shared__ float rp[4], rl[4];
        if (lane == 0) { rp[wave] = sp; rl[wave] = sl; }
        __syncthreads();
        if (t == 0) {
            float P = rp[0] + rp[1] + rp[2] + rp[3];
            float L = rl[0] + rl[1] + rl[2] + rl[3];
            out[0] = (L - P) / 16384.0f;
        }
    }
}

extern "C" void kernel_launch(void* const* d_in, const int* in_sizes, int n_in,
                              void* d_out, int out_size, void* d_ws, size_t ws_size,
                              hipStream_t stream) {
    const float* z1 = (const float*)d_in[0];
    const float* z2 = (const float*)d_in[1];
    const float* z3 = (const float*)d_in[2];
    const float* z4 = (const float*)d_in[3];
    float* out = (float*)d_out;

    const size_t PART_OFF = (size_t)(8u << 20);   // 8 MB: part [128][16384] f32 = 8 MB
    const size_t POS_OFF  = (size_t)(16u << 20);  // 16 KB
    const size_t LOG_OFF  = POS_OFF + 16384;      // 1 KB (256 floats)
    const size_t CNT_OFF  = LOG_OFF + 1024;

    char* ws = (char*)d_ws;
    bf16*  zb      = (bf16*)ws;
    float* part    = (float*)(ws + PART_OFF);
    float* pospart = (float*)(ws + POS_OFF);
    float* logpart = (float*)(ws + LOG_OFF);
    unsigned* cnt  = (unsigned*)(ws + CNT_OFF);

    norm4k<<<1024, 256, 0, stream>>>(z1, z2, z3, z4, zb, pospart, cnt);
    tilek<<<8256, 256, 0, stream>>>(zb, part);
    rowlogf<<<256, 256, 0, stream>>>(part, pospart, logpart, cnt, out);
}